// Round 11
// baseline (158.865 us; speedup 1.0000x reference)
//
#include <hip/hip_runtime.h>
#include <math.h>

#define L_SEQ 4096
#define C_DIM 256
#define H_HEADS 8
#define K_MAX 64
#define D_HEAD 32
#define HALF_W 32
#define N_OFF 65          // 2*HALF_W + 1
#define HK 512            // H_HEADS * K_MAX

__device__ __forceinline__ float sigmoidf_(float x) { return 1.0f / (1.0f + expf(-x)); }

// ================= K1: fused projection GEMM (unchanged from round 10) =================
// BM=128, BN=64, BK=16, TM=8, TN=4, 256 threads, grid (12, 32) = 384.
__global__ void __launch_bounds__(256, 2)
proj_gemm(const float* __restrict__ A, const float* __restrict__ kw_w,
          const float* __restrict__ vw, const float* __restrict__ kb,
          const float* __restrict__ vb,
          float* __restrict__ kwbuf, float* __restrict__ vbuf) {
    __shared__ float As[16][132];
    __shared__ float Bs[16][68];

    const int tid = threadIdx.x;
    const int tx = tid & 15;
    const int ty = tid >> 4;
    const int l0 = blockIdx.y * 128;
    const int n0 = blockIdx.x * 64;

    const int ar0 = tid >> 2;
    const int ac0 = (tid & 3) * 4;
    const int ar1 = ar0 + 64;
    const int bk = tid >> 4;
    const int bn = (tid & 15) * 4;

    const float* Bsrc;
    int ldb, coff;
    if (n0 < 512) { Bsrc = kw_w; ldb = 512; coff = n0; }
    else          { Bsrc = vw;   ldb = 256; coff = n0 - 512; }

    float acc[8][4];
#pragma unroll
    for (int i = 0; i < 8; ++i)
#pragma unroll
        for (int jj = 0; jj < 4; ++jj) acc[i][jj] = 0.0f;

    float4 av0 = *(const float4*)&A[(l0 + ar0) * C_DIM + ac0];
    float4 av1 = *(const float4*)&A[(l0 + ar1) * C_DIM + ac0];
    float4 bv  = *(const float4*)&Bsrc[bk * ldb + coff + bn];

    for (int k0 = 0; k0 < C_DIM; k0 += 16) {
        __syncthreads();
        As[ac0 + 0][ar0] = av0.x;
        As[ac0 + 1][ar0] = av0.y;
        As[ac0 + 2][ar0] = av0.z;
        As[ac0 + 3][ar0] = av0.w;
        As[ac0 + 0][ar1] = av1.x;
        As[ac0 + 1][ar1] = av1.y;
        As[ac0 + 2][ar1] = av1.z;
        As[ac0 + 3][ar1] = av1.w;
        *(float4*)&Bs[bk][bn] = bv;
        __syncthreads();
        if (k0 + 16 < C_DIM) {
            av0 = *(const float4*)&A[(l0 + ar0) * C_DIM + (k0 + 16) + ac0];
            av1 = *(const float4*)&A[(l0 + ar1) * C_DIM + (k0 + 16) + ac0];
            bv  = *(const float4*)&Bsrc[(k0 + 16 + bk) * ldb + coff + bn];
        }
#pragma unroll
        for (int kk = 0; kk < 16; ++kk) {
            const float4 a4lo = *(const float4*)&As[kk][ty * 8];
            const float4 a4hi = *(const float4*)&As[kk][ty * 8 + 4];
            const float4 b4   = *(const float4*)&Bs[kk][tx * 4];
            const float ar[8] = {a4lo.x, a4lo.y, a4lo.z, a4lo.w,
                                 a4hi.x, a4hi.y, a4hi.z, a4hi.w};
            const float br[4] = {b4.x, b4.y, b4.z, b4.w};
#pragma unroll
            for (int i = 0; i < 8; ++i)
#pragma unroll
                for (int jj = 0; jj < 4; ++jj)
                    acc[i][jj] = fmaf(ar[i], br[jj], acc[i][jj]);
        }
    }

    const int g0 = n0 + tx * 4;
    float4 bz;
    float* dst;
    int stride, col;
    if (g0 < 512) { bz = *(const float4*)&kb[g0];       dst = kwbuf; stride = 512; col = g0; }
    else          { bz = *(const float4*)&vb[g0 - 512]; dst = vbuf;  stride = 256; col = g0 - 512; }
#pragma unroll
    for (int i = 0; i < 8; ++i) {
        const int row = l0 + ty * 8 + i;
        float4 o;
        o.x = acc[i][0] + bz.x;
        o.y = acc[i][1] + bz.y;
        o.z = acc[i][2] + bz.z;
        o.w = acc[i][3] + bz.w;
        *(float4*)&dst[row * stride + col] = o;
    }
}

// ================= K2: fused norm + small-proj + conv, 2 ROWS PER BLOCK =================
// 256 threads, grid 2048. Per-row arithmetic bitwise == round 10:
//  - waves 2-3 load kwraw squares while waves 0-1 run both rows' small-projs
//  - rmsnorm tree: 2 LDS steps + 6-step shfl_xor butterfly (pair sums commute
//    -> bitwise == the red[j]+=red[j+s] tree)
//  - stage 2 (16 serial denominators, tid<16) runs parallel with stage 1.5
//  - stage 3: dual-row interleaved fmaf chains (each chain order == round 10)
__global__ void __launch_bounds__(256, 2)
conv_fused(const float* __restrict__ x,
           const float* __restrict__ ww, const float* __restrict__ wb,
           const float* __restrict__ wg,
           const float* __restrict__ ow, const float* __restrict__ ob,
           const float* __restrict__ og,
           const float* __restrict__ kg,
           const float* __restrict__ kwraw, const float* __restrict__ v,
           float* __restrict__ out) {
    const int l0 = blockIdx.x * 2;
    const int tid = threadIdx.x;

    __shared__ float2 red2[256];
    __shared__ float2 rs_s2;
    __shared__ float kwrow[2][HK];
    __shared__ float wsz[2][H_HEADS], ofs[2][H_HEADS];
    __shared__ float4 tap[2][H_HEADS][N_OFF];
    __shared__ float2 warr[2][H_HEADS][N_OFF + 1];
    __shared__ float inv_denom[2][H_HEADS];
    __shared__ int okflag;

    if (tid == 0) okflag = 1;

    // ---- Segment 1: waves 2-3 = phase-A loads (both rows); waves 0-1 = phase B ----
    float z00a = 0, z00b = 0, z01a = 0, z01b = 0;
    float z10a = 0, z10b = 0, z11a = 0, z11b = 0;
    if (tid >= 128) {
        const int j0 = tid - 128, j1 = tid;
        const float* r0 = kwraw + l0 * HK;
        const float* r1 = kwraw + (l0 + 1) * HK;
        z00a = r0[j0]; z00b = r0[j0 + 256];
        z01a = r0[j1]; z01b = r0[j1 + 256];
        z10a = r1[j0]; z10b = r1[j0 + 256];
        z11a = r1[j1]; z11b = r1[j1 + 256];
        red2[j0] = make_float2(z00a * z00a + z00b * z00b, z10a * z10a + z10b * z10b);
        red2[j1] = make_float2(z01a * z01a + z01b * z01b, z11a * z11a + z11b * z11b);
    } else {
        // Phase B: wave r handles row l0+r (bitwise == round-10 wave-0 body)
        const int r = tid >> 6;
        const int lane = tid & 63;
        const float* xr = x + (l0 + r) * C_DIM;
        float accw[H_HEADS], acco[H_HEADS];
#pragma unroll
        for (int h = 0; h < H_HEADS; ++h) { accw[h] = 0.0f; acco[h] = 0.0f; }
#pragma unroll
        for (int i = 0; i < C_DIM / 64; ++i) {
            const int c = lane + i * 64;
            const float xv = xr[c];
            const float* wwc = ww + c * H_HEADS;
            const float* owc = ow + c * H_HEADS;
#pragma unroll
            for (int h = 0; h < H_HEADS; ++h) {
                accw[h] = fmaf(xv, wwc[h], accw[h]);
                acco[h] = fmaf(xv, owc[h], acco[h]);
            }
        }
#pragma unroll
        for (int off = 32; off > 0; off >>= 1) {
#pragma unroll
            for (int h = 0; h < H_HEADS; ++h) {
                accw[h] += __shfl_xor(accw[h], off);
                acco[h] += __shfl_xor(acco[h], off);
            }
        }
        if (lane < H_HEADS) {
            float zw[H_HEADS], zo[H_HEADS];
            float ssw = 0.0f, sso = 0.0f;
#pragma unroll
            for (int h = 0; h < H_HEADS; ++h) {
                zw[h] = accw[h] + wb[h];
                zo[h] = acco[h] + ob[h];
                ssw += zw[h] * zw[h];
                sso += zo[h] * zo[h];
            }
            const float rw = rsqrtf(ssw / (float)H_HEADS + 1e-6f);
            const float ro = rsqrtf(sso / (float)H_HEADS + 1e-6f);
            const float nw = wg[lane] * zw[lane] * rw;
            const float no = og[lane] * zo[lane] * ro;
            wsz[r][lane] = 1.0f + sigmoidf_(nw) * 63.0f;
            ofs[r][lane] = tanhf(no) * 64.0f;
        }
    }
    __syncthreads();

    // ---- rmsnorm reduction: s=128 (LDS), s=64 (LDS), then wave-0 butterfly ----
    if (tid < 128) {
        const float2 a = red2[tid], b = red2[tid + 128];
        red2[tid] = make_float2(a.x + b.x, a.y + b.y);
    }
    __syncthreads();
    if (tid < 64) {
        float sx = red2[tid].x + red2[tid + 64].x;
        float sy = red2[tid].y + red2[tid + 64].y;
#pragma unroll
        for (int off = 32; off > 0; off >>= 1) {
            sx += __shfl_xor(sx, off);
            sy += __shfl_xor(sy, off);
        }
        if (tid == 0)
            rs_s2 = make_float2(rsqrtf(sx / (float)HK + 1e-6f),
                                rsqrtf(sy / (float)HK + 1e-6f));
    }
    __syncthreads();

    // ---- rmsnorm epilogue (waves 2-3 hold the z values) ----
    if (tid >= 128) {
        const int j0 = tid - 128, j1 = tid;
        const float rs0 = rs_s2.x, rs1 = rs_s2.y;
        float n;
        n = kg[j0]       * z00a * rs0; kwrow[0][j0]       = n * sigmoidf_(n);
        n = kg[j0 + 256] * z00b * rs0; kwrow[0][j0 + 256] = n * sigmoidf_(n);
        n = kg[j1]       * z01a * rs0; kwrow[0][j1]       = n * sigmoidf_(n);
        n = kg[j1 + 256] * z01b * rs0; kwrow[0][j1 + 256] = n * sigmoidf_(n);
        n = kg[j0]       * z10a * rs1; kwrow[1][j0]       = n * sigmoidf_(n);
        n = kg[j0 + 256] * z10b * rs1; kwrow[1][j0 + 256] = n * sigmoidf_(n);
        n = kg[j1]       * z11a * rs1; kwrow[1][j1]       = n * sigmoidf_(n);
        n = kg[j1 + 256] * z11b * rs1; kwrow[1][j1 + 256] = n * sigmoidf_(n);
    }
    __syncthreads();

    // ---- Stage 1: attention taps, both rows (expressions bitwise == round 10) ----
    for (int t = tid; t < 2 * H_HEADS * N_OFF; t += 256) {
        const int r = t / (H_HEADS * N_OFF);
        const int t2 = t - r * (H_HEADS * N_OFF);
        const int h = t2 / N_OFF;
        const int n = t2 - h * N_OFF;
        const int l = l0 + r;
        const float ws  = wsz[r][h];
        const float off = ofs[r][h];
        const float local = (float)(n - HALF_W);
        const float neighbor = (float)l + off + local;
        const bool valid = (neighbor >= 0.0f) && (neighbor < (float)L_SEQ);
        const float nc = fminf(fmaxf(neighbor, 0.0f), (float)(L_SEQ - 1));

        const float rel = fabsf(local) / (ws * 0.5f + 1e-6f);
        const float mask = sigmoidf_(5.0f * (1.0f - rel)) * (valid ? 1.0f : 0.0f);

        const float kidx = fminf(rel, 1.0f) * (float)(K_MAX - 1);
        int ifl = (int)kidx;
        ifl = min(ifl, K_MAX - 2);
        const float wce = kidx - (float)ifl;
        const float kf = kwrow[r][h * K_MAX + ifl];
        const float kc = kwrow[r][h * K_MAX + ifl + 1];
        const float attnv = (kf * (1.0f - wce) + kc * wce) * mask;

        int p = (int)floorf(nc);
        p = min(max(p, 0), L_SEQ - 1);
        const int pc = min(p + 1, L_SEQ - 1);
        const float fr = nc - (float)p;

        float4 tv;
        tv.x = attnv;
        tv.y = fr;
        tv.z = __int_as_float(p * C_DIM + h * D_HEAD);
        tv.w = __int_as_float(pc * C_DIM + h * D_HEAD);
        tap[r][h][n] = tv;
    }
    __syncthreads();

    // ---- Stage 2 (tid<16, serial n order == round 10) || Stage 1.5 (rest) ----
    if (tid < 16) {
        const int r = tid >> 3, h = tid & 7;
        float s = 0.0f;
        for (int n = 0; n < N_OFF; ++n) s += tap[r][h][n].x;
        inv_denom[r][h] = 1.0f / (s + 1e-6f);
    } else {
        for (int t = tid - 16; t < 2 * H_HEADS * (N_OFF + 1); t += 240) {
            const int r = t / (H_HEADS * (N_OFF + 1));
            const int t2 = t - r * (H_HEADS * (N_OFF + 1));
            const int h = t2 / (N_OFF + 1);
            const int m = t2 - h * (N_OFF + 1);
            float w, rowf;
            if (m == 0) {
                const float4 cur = tap[r][h][0];
                w = cur.x * (1.0f - cur.y);
                rowf = cur.z;
            } else {
                const float4 prev = tap[r][h][m - 1];
                const float wc = prev.x * prev.y;
                if (m < N_OFF) {
                    const float4 cur = tap[r][h][m];
                    w = cur.x * (1.0f - cur.y) + wc;
                    rowf = cur.z;
                    if (wc != 0.0f && __float_as_int(prev.w) != __float_as_int(cur.z))
                        okflag = 0;   // benign race: all writers store 0
                } else {
                    w = wc;
                    rowf = prev.w;
                }
            }
            warr[r][h][m] = make_float2(w, rowf);
        }
    }
    __syncthreads();

    // ---- Stage 3: dual-row interleaved gather/accumulate ----
    const int h = tid >> 5;
    const int d = tid & 31;
    float acc0 = 0.0f, acc1 = 0.0f;
    if (okflag) {
#pragma unroll 3
        for (int m = 0; m < N_OFF + 1; ++m) {
            const float2 ta = warr[0][h][m];
            const float2 tb = warr[1][h][m];
            acc0 = fmaf(ta.x, v[__float_as_int(ta.y) + d], acc0);
            acc1 = fmaf(tb.x, v[__float_as_int(tb.y) + d], acc1);
        }
    } else {
#pragma unroll 3
        for (int n = 0; n < N_OFF; ++n) {
            const float4 t4a = tap[0][h][n];
            const float4 t4b = tap[1][h][n];
            float vf = v[__float_as_int(t4a.z) + d];
            float vc = v[__float_as_int(t4a.w) + d];
            acc0 = fmaf(t4a.x, fmaf(t4a.y, vc - vf, vf), acc0);
            vf = v[__float_as_int(t4b.z) + d];
            vc = v[__float_as_int(t4b.w) + d];
            acc1 = fmaf(t4b.x, fmaf(t4b.y, vc - vf, vf), acc1);
        }
    }
    out[l0 * C_DIM + h * D_HEAD + d]       = acc0 * inv_denom[0][h];
    out[(l0 + 1) * C_DIM + h * D_HEAD + d] = acc1 * inv_denom[1][h];
}

// ================= K3: out projection GEMM + silu (unchanged from round 10) =================
__global__ void __launch_bounds__(256, 4)
out_gemm(const float* __restrict__ A, const float* __restrict__ W,
         float* __restrict__ out) {
    __shared__ float As[16][68];
    __shared__ float Bs[16][68];

    const int tid = threadIdx.x;
    const int tx = tid & 15;
    const int ty = tid >> 4;
    const int l0 = blockIdx.y * 64;
    const int n0 = blockIdx.x * 64;

    const int am = tid >> 2;
    const int ak = (tid & 3) * 4;
    const int bk = tid >> 4;
    const int bn = (tid & 15) * 4;

    float acc[4][4];
#pragma unroll
    for (int i = 0; i < 4; ++i)
#pragma unroll
        for (int jj = 0; jj < 4; ++jj) acc[i][jj] = 0.0f;

    float4 av = *(const float4*)&A[(l0 + am) * C_DIM + ak];
    float4 bv = *(const float4*)&W[bk * C_DIM + n0 + bn];

    for (int k0 = 0; k0 < C_DIM; k0 += 16) {
        __syncthreads();
        As[ak + 0][am] = av.x;
        As[ak + 1][am] = av.y;
        As[ak + 2][am] = av.z;
        As[ak + 3][am] = av.w;
        *(float4*)&Bs[bk][bn] = bv;
        __syncthreads();
        if (k0 + 16 < C_DIM) {
            av = *(const float4*)&A[(l0 + am) * C_DIM + (k0 + 16) + ak];
            bv = *(const float4*)&W[(k0 + 16 + bk) * C_DIM + n0 + bn];
        }
#pragma unroll
        for (int kk = 0; kk < 16; ++kk) {
            const float4 a4 = *(const float4*)&As[kk][ty * 4];
            const float4 b4 = *(const float4*)&Bs[kk][tx * 4];
            const float ar[4] = {a4.x, a4.y, a4.z, a4.w};
            const float br[4] = {b4.x, b4.y, b4.z, b4.w};
#pragma unroll
            for (int i = 0; i < 4; ++i)
#pragma unroll
                for (int jj = 0; jj < 4; ++jj)
                    acc[i][jj] = fmaf(ar[i], br[jj], acc[i][jj]);
        }
    }

    const int g0 = n0 + tx * 4;
#pragma unroll
    for (int i = 0; i < 4; ++i) {
        const int row = l0 + ty * 4 + i;
        float4 o;
        o.x = acc[i][0] * sigmoidf_(acc[i][0]);
        o.y = acc[i][1] * sigmoidf_(acc[i][1]);
        o.z = acc[i][2] * sigmoidf_(acc[i][2]);
        o.w = acc[i][3] * sigmoidf_(acc[i][3]);
        *(float4*)&out[row * C_DIM + g0] = o;
    }
}

extern "C" void kernel_launch(void* const* d_in, const int* in_sizes, int n_in,
                              void* d_out, int out_size, void* d_ws, size_t ws_size,
                              hipStream_t stream) {
    const float* x    = (const float*)d_in[0];
    const float* ww   = (const float*)d_in[1];
    const float* wb   = (const float*)d_in[2];
    const float* wg   = (const float*)d_in[3];
    const float* ow   = (const float*)d_in[4];
    const float* ob   = (const float*)d_in[5];
    const float* og   = (const float*)d_in[6];
    const float* kw_w = (const float*)d_in[7];
    const float* kb   = (const float*)d_in[8];
    const float* kg   = (const float*)d_in[9];
    const float* vw   = (const float*)d_in[10];
    const float* vb   = (const float*)d_in[11];
    const float* outw = (const float*)d_in[12];
    float* y = (float*)d_out;

    float* ws_f    = (float*)d_ws;
    float* kwbuf   = ws_f;                       // 4096*512 (raw z+bias)
    float* vbuf    = kwbuf + L_SEQ * HK;         // 4096*256
    float* convbuf = vbuf + L_SEQ * C_DIM;       // 4096*256

    proj_gemm<<<dim3(12, L_SEQ / 128), 256, 0, stream>>>(x, kw_w, vw, kb, vb, kwbuf, vbuf);
    conv_fused<<<L_SEQ / 2, 256, 0, stream>>>(x, ww, wb, wg, ow, ob, og, kg, kwbuf, vbuf, convbuf);
    out_gemm<<<dim3(C_DIM / 64, L_SEQ / 64), 256, 0, stream>>>(convbuf, outw, y);
}